// Round 1
// baseline (825.418 us; speedup 1.0000x reference)
//
#include <hip/hip_runtime.h>
#include <hip/hip_bf16.h>

typedef __bf16 bf16x8 __attribute__((ext_vector_type(8)));
typedef float floatx4 __attribute__((ext_vector_type(4)));

#define AS1 __attribute__((address_space(1)))
#define AS3 __attribute__((address_space(3)))

// ---------------------------------------------------------------- cvt A fp32 -> bf16
__global__ __launch_bounds__(256) void cvt_a_kernel(const float* __restrict__ A,
                                                    __hip_bfloat16* __restrict__ Ab,
                                                    int n8) {
    int i = blockIdx.x * 256 + threadIdx.x;
    if (i >= n8) return;
    size_t base = (size_t)i * 8;
    float4 a0 = *(const float4*)(A + base);
    float4 a1 = *(const float4*)(A + base + 4);
    union { __hip_bfloat16 h[8]; float4 f; } u;
    u.h[0] = __float2bfloat16(a0.x);
    u.h[1] = __float2bfloat16(a0.y);
    u.h[2] = __float2bfloat16(a0.z);
    u.h[3] = __float2bfloat16(a0.w);
    u.h[4] = __float2bfloat16(a1.x);
    u.h[5] = __float2bfloat16(a1.y);
    u.h[6] = __float2bfloat16(a1.z);
    u.h[7] = __float2bfloat16(a1.w);
    *(float4*)(Ab + base) = u.f;
}

// ---------------------------------------------------------------- dequant B -> Wt bf16 [N][K]
// Bp: int32 [T][2N]  (T = K/16; pair of int32 per (t,n) = 16 input rows)
// s : fp32  [K/128][N]
// Each block: 16 t x 16 n tile; LDS transpose so reads (n-fast) and writes
// (t-fast, 32 B/thread down a Wt column) both coalesce.
__global__ __launch_bounds__(256) void dequant_kernel(const int* __restrict__ Bp,
                                                      const float* __restrict__ s,
                                                      __hip_bfloat16* __restrict__ Wt,
                                                      int N, int T) {
    __shared__ __hip_bfloat16 tile[16 * 16 * 16];  // [nl][tl][r]
    const int tid = threadIdx.x;
    const int t0 = blockIdx.x * 16;
    const int n0 = blockIdx.y * 16;
    {
        const int nl = tid & 15, tl = tid >> 4;
        const int t = t0 + tl, n = n0 + nl;
        const int* p = Bp + (size_t)t * (2 * N) + 2 * n;
        const unsigned lo = (unsigned)p[0];
        const unsigned hi = (unsigned)p[1];
        const float sc = s[(size_t)(t >> 3) * N + n];  // group row = t*16/128 = t/8
        __hip_bfloat16* dst = &tile[(nl * 16 + tl) * 16];
#pragma unroll
        for (int r = 0; r < 8; ++r) {
            dst[r]     = __float2bfloat16(((float)((lo >> (4 * r)) & 0xFu) - 8.0f) * sc);
            dst[r + 8] = __float2bfloat16(((float)((hi >> (4 * r)) & 0xFu) - 8.0f) * sc);
        }
    }
    __syncthreads();
    {
        const int tl = tid & 15, nl = tid >> 4;
        const float4* src = (const float4*)&tile[(nl * 16 + tl) * 16];
        float4* dst = (float4*)(Wt + (size_t)(n0 + nl) * ((size_t)T * 16) + (size_t)(t0 + tl) * 16);
        dst[0] = src[0];
        dst[1] = src[1];
    }
}

// ---------------------------------------------------------------- GEMM C = A * Wt^T + bias
// A  bf16 [M][K] row-major, Bt bf16 [N][K] row-major (i.e. W^T), C fp32 [M][N].
// 128x128 block tile, BK=64, 256 thr = 4 waves in 2x2, each wave 64x64 via
// 4x4 grid of 16x16x32 bf16 MFMA. global_load_lds width=16 staging (m97).
__global__ __launch_bounds__(256) void gemm_bt_kernel(const __hip_bfloat16* __restrict__ A,
                                                      const __hip_bfloat16* __restrict__ Bt,
                                                      const float* __restrict__ bias,
                                                      float* __restrict__ C,
                                                      int M, int N, int K) {
    __shared__ __hip_bfloat16 As[128 * 64];
    __shared__ __hip_bfloat16 Bs[128 * 64];

    const int tid = threadIdx.x;
    const int wave = tid >> 6;
    const int lane = tid & 63;
    const int m0 = blockIdx.y * 128;
    const int n0 = blockIdx.x * 128;
    const int wm = wave >> 1;  // 0..1
    const int wn = wave & 1;   // 0..1

    floatx4 acc[4][4];
#pragma unroll
    for (int i = 0; i < 4; ++i)
#pragma unroll
        for (int j = 0; j < 4; ++j) acc[i][j] = (floatx4){0.f, 0.f, 0.f, 0.f};

    // staging: wave covers 8 rows per issue (8 lanes x 16B per row of 128B)
    const int ldrow = wave * 8 + (lane >> 3);  // 0..31
    const int ldcol = (lane & 7) * 8;          // bf16 element offset (16B chunks)
    const __hip_bfloat16* Aldg = A + (size_t)(m0 + ldrow) * K + ldcol;
    const __hip_bfloat16* Bldg = Bt + (size_t)(n0 + ldrow) * K + ldcol;
    __hip_bfloat16* AsBase = &As[(wave * 8) * 64];  // wave-uniform LDS dst base
    __hip_bfloat16* BsBase = &Bs[(wave * 8) * 64];

    for (int k0 = 0; k0 < K; k0 += 64) {
#pragma unroll
        for (int i = 0; i < 4; ++i) {
            __builtin_amdgcn_global_load_lds((AS1 void*)(Aldg + (size_t)(i * 32) * K + k0),
                                             (AS3 void*)(AsBase + i * 32 * 64), 16, 0, 0);
            __builtin_amdgcn_global_load_lds((AS1 void*)(Bldg + (size_t)(i * 32) * K + k0),
                                             (AS3 void*)(BsBase + i * 32 * 64), 16, 0, 0);
        }
        __syncthreads();  // drains vmcnt(0) then barrier

#pragma unroll
        for (int ks = 0; ks < 2; ++ks) {
            const int koff = ks * 32 + (lane >> 4) * 8;  // A[m][k]: m=lane&15, k=quad*8+j
            bf16x8 af[4], bfr[4];
#pragma unroll
            for (int i = 0; i < 4; ++i)
                af[i] = *(const bf16x8*)&As[(wm * 64 + i * 16 + (lane & 15)) * 64 + koff];
#pragma unroll
            for (int j = 0; j < 4; ++j)
                bfr[j] = *(const bf16x8*)&Bs[(wn * 64 + j * 16 + (lane & 15)) * 64 + koff];
#pragma unroll
            for (int i = 0; i < 4; ++i)
#pragma unroll
                for (int j = 0; j < 4; ++j)
                    acc[i][j] = __builtin_amdgcn_mfma_f32_16x16x32_bf16(af[i], bfr[j],
                                                                        acc[i][j], 0, 0, 0);
        }
        __syncthreads();
    }

    // epilogue: C/D layout col=lane&15, row=(lane>>4)*4+reg  [m89-verified]
    const int cl = lane & 15;
    const int rq = (lane >> 4) * 4;
#pragma unroll
    for (int j = 0; j < 4; ++j) {
        const int n = n0 + wn * 64 + j * 16 + cl;
        const float bv = bias[n];
#pragma unroll
        for (int i = 0; i < 4; ++i) {
            const int mbase = m0 + wm * 64 + i * 16 + rq;
#pragma unroll
            for (int r = 0; r < 4; ++r)
                C[(size_t)(mbase + r) * N + n] = acc[i][j][r] + bv;
        }
    }
}

// ---------------------------------------------------------------- launch
extern "C" void kernel_launch(void* const* d_in, const int* in_sizes, int n_in,
                              void* d_out, int out_size, void* d_ws, size_t ws_size,
                              hipStream_t stream) {
    const float* A = (const float*)d_in[0];
    const int* Bp = (const int*)d_in[1];
    const float* s = (const float*)d_in[2];
    const float* bias = (const float*)d_in[3];
    float* C = (float*)d_out;

    const int N = in_sizes[3];                        // 12288
    const long Bsz = (long)in_sizes[1];               // (K/16)*(2N)
    const int K = (int)(Bsz / (2L * N)) * 16;         // 4096
    const int M = (int)((long)in_sizes[0] / K);       // 4096
    const int T = K / 16;

    __hip_bfloat16* Ab = (__hip_bfloat16*)d_ws;                               // M*K*2 B
    __hip_bfloat16* Wt = (__hip_bfloat16*)((char*)d_ws + (size_t)M * K * 2);  // N*K*2 B

    const int n8 = (M * K) / 8;
    cvt_a_kernel<<<(n8 + 255) / 256, 256, 0, stream>>>(A, Ab, n8);
    dequant_kernel<<<dim3(T / 16, N / 16), 256, 0, stream>>>(Bp, s, Wt, N, T);
    gemm_bt_kernel<<<dim3(N / 128, M / 128), 256, 0, stream>>>(Ab, Wt, bias, C, M, N, K);
}

// Round 2
// 761.122 us; speedup vs baseline: 1.0845x; 1.0845x over previous
//
#include <hip/hip_runtime.h>
#include <hip/hip_bf16.h>

typedef __bf16 bf16x8 __attribute__((ext_vector_type(8)));
typedef float floatx4 __attribute__((ext_vector_type(4)));

#define AS1 __attribute__((address_space(1)))
#define AS3 __attribute__((address_space(3)))

// ---------------------------------------------------------------- cvt A fp32 -> bf16
__global__ __launch_bounds__(256) void cvt_a_kernel(const float* __restrict__ A,
                                                    __hip_bfloat16* __restrict__ Ab,
                                                    int n8) {
    int i = blockIdx.x * 256 + threadIdx.x;
    if (i >= n8) return;
    size_t base = (size_t)i * 8;
    float4 a0 = *(const float4*)(A + base);
    float4 a1 = *(const float4*)(A + base + 4);
    union { __hip_bfloat16 h[8]; float4 f; } u;
    u.h[0] = __float2bfloat16(a0.x);
    u.h[1] = __float2bfloat16(a0.y);
    u.h[2] = __float2bfloat16(a0.z);
    u.h[3] = __float2bfloat16(a0.w);
    u.h[4] = __float2bfloat16(a1.x);
    u.h[5] = __float2bfloat16(a1.y);
    u.h[6] = __float2bfloat16(a1.z);
    u.h[7] = __float2bfloat16(a1.w);
    *(float4*)(Ab + base) = u.f;
}

// ---------------------------------------------------------------- dequant B -> Wt bf16 [N][K]
// No LDS. Thread map t-fast: each thread owns (t,n), writes its 32 B
// Wt[n][16t..16t+15] chunk; consecutive lanes -> consecutive 32 B (coalesced).
// Packed reads: wave touches 16 distinct 128 B lines, each shared by 4 lanes
// (8 B apart) -> VMEM-coalesced per line, 24 MB total, L2-friendly.
__global__ __launch_bounds__(256) void dequant_kernel(const int* __restrict__ Bp,
                                                      const float* __restrict__ s,
                                                      __hip_bfloat16* __restrict__ Wt,
                                                      int N, int T) {
    const int tid = threadIdx.x;
    const int tl = tid & 15;   // t fast -> coalesced Wt writes
    const int nl = tid >> 4;
    const int t = blockIdx.x * 16 + tl;
    const int n = blockIdx.y * 16 + nl;
    const int2 p = *(const int2*)(Bp + (size_t)t * (2 * N) + 2 * n);
    const unsigned lo = (unsigned)p.x;
    const unsigned hi = (unsigned)p.y;
    const float sc = s[(size_t)(t >> 3) * N + n];  // group row = t*16/128 = t/8
    union { __hip_bfloat16 h[16]; float4 f[2]; } u;
#pragma unroll
    for (int r = 0; r < 8; ++r) {
        u.h[r]     = __float2bfloat16(((float)((lo >> (4 * r)) & 0xFu) - 8.0f) * sc);
        u.h[r + 8] = __float2bfloat16(((float)((hi >> (4 * r)) & 0xFu) - 8.0f) * sc);
    }
    float4* dst = (float4*)(Wt + (size_t)n * ((size_t)T * 16) + (size_t)t * 16);
    dst[0] = u.f[0];
    dst[1] = u.f[1];
}

// ---------------------------------------------------------------- GEMM C = A * Wt^T + bias
// A  bf16 [M][K] row-major, Bt bf16 [N][K] row-major (i.e. W^T), C fp32 [M][N].
// 128x128 block tile, BK=64, 256 thr = 4 waves in 2x2, each wave 64x64 via
// 4x4 grid of 16x16x32 bf16 MFMA. global_load_lds width=16 staging (m97).
//
// LDS bank-conflict fix: rows are 128 B = exactly 32 dwords, so an unswizzled
// fragment read is 16-way conflicted within each quad (R1: 1.5e8 conflict
// cycles). Since global_load_lds forces lane L -> base + L*16B, we swizzle on
// the GLOBAL side instead: lane fetches chunk (c ^ (row&7)), so
// LDS(row, c) == global(row, c ^ (row&7)). The fragment read applies the
// inverse: chunk = (ks*4 + quad) ^ (lane&7) -> banks spread, 2-way max (free).
__global__ __launch_bounds__(256) void gemm_bt_kernel(const __hip_bfloat16* __restrict__ A,
                                                      const __hip_bfloat16* __restrict__ Bt,
                                                      const float* __restrict__ bias,
                                                      float* __restrict__ C,
                                                      int M, int N, int K) {
    __shared__ __hip_bfloat16 As[128 * 64];
    __shared__ __hip_bfloat16 Bs[128 * 64];

    const int tid = threadIdx.x;
    const int wave = tid >> 6;
    const int lane = tid & 63;
    const int m0 = blockIdx.y * 128;
    const int n0 = blockIdx.x * 128;
    const int wm = wave >> 1;  // 0..1
    const int wn = wave & 1;   // 0..1

    floatx4 acc[4][4];
#pragma unroll
    for (int i = 0; i < 4; ++i)
#pragma unroll
        for (int j = 0; j < 4; ++j) acc[i][j] = (floatx4){0.f, 0.f, 0.f, 0.f};

    // staging: wave covers 8 rows per issue (8 lanes x 16B per row of 128B)
    const int ldrow = wave * 8 + (lane >> 3);              // 0..31
    const int swz = lane >> 3;                             // = ldrow & 7
    const int ldcol = (((lane & 7) ^ swz)) * 8;            // swizzled 16B chunk
    const __hip_bfloat16* Aldg = A + (size_t)(m0 + ldrow) * K + ldcol;
    const __hip_bfloat16* Bldg = Bt + (size_t)(n0 + ldrow) * K + ldcol;
    __hip_bfloat16* AsBase = &As[(wave * 8) * 64];  // wave-uniform LDS dst base
    __hip_bfloat16* BsBase = &Bs[(wave * 8) * 64];

    for (int k0 = 0; k0 < K; k0 += 64) {
#pragma unroll
        for (int i = 0; i < 4; ++i) {
            __builtin_amdgcn_global_load_lds((AS1 void*)(Aldg + (size_t)(i * 32) * K + k0),
                                             (AS3 void*)(AsBase + i * 32 * 64), 16, 0, 0);
            __builtin_amdgcn_global_load_lds((AS1 void*)(Bldg + (size_t)(i * 32) * K + k0),
                                             (AS3 void*)(BsBase + i * 32 * 64), 16, 0, 0);
        }
        __syncthreads();  // drains vmcnt(0) then barrier

#pragma unroll
        for (int ks = 0; ks < 2; ++ks) {
            // global chunk t = ks*4 + quad; LDS chunk = t ^ (m_row & 7),
            // m_row & 7 == lane & 7 (wm*64, i*16 are multiples of 8)
            const int koff = ((ks * 4 + (lane >> 4)) ^ (lane & 7)) * 8;
            bf16x8 af[4], bfr[4];
#pragma unroll
            for (int i = 0; i < 4; ++i)
                af[i] = *(const bf16x8*)&As[(wm * 64 + i * 16 + (lane & 15)) * 64 + koff];
#pragma unroll
            for (int j = 0; j < 4; ++j)
                bfr[j] = *(const bf16x8*)&Bs[(wn * 64 + j * 16 + (lane & 15)) * 64 + koff];
#pragma unroll
            for (int i = 0; i < 4; ++i)
#pragma unroll
                for (int j = 0; j < 4; ++j)
                    acc[i][j] = __builtin_amdgcn_mfma_f32_16x16x32_bf16(af[i], bfr[j],
                                                                        acc[i][j], 0, 0, 0);
        }
        __syncthreads();
    }

    // epilogue: C/D layout col=lane&15, row=(lane>>4)*4+reg  [m89-verified]
    const int cl = lane & 15;
    const int rq = (lane >> 4) * 4;
#pragma unroll
    for (int j = 0; j < 4; ++j) {
        const int n = n0 + wn * 64 + j * 16 + cl;
        const float bv = bias[n];
#pragma unroll
        for (int i = 0; i < 4; ++i) {
            const int mbase = m0 + wm * 64 + i * 16 + rq;
#pragma unroll
            for (int r = 0; r < 4; ++r)
                C[(size_t)(mbase + r) * N + n] = acc[i][j][r] + bv;
        }
    }
}

// ---------------------------------------------------------------- launch
extern "C" void kernel_launch(void* const* d_in, const int* in_sizes, int n_in,
                              void* d_out, int out_size, void* d_ws, size_t ws_size,
                              hipStream_t stream) {
    const float* A = (const float*)d_in[0];
    const int* Bp = (const int*)d_in[1];
    const float* s = (const float*)d_in[2];
    const float* bias = (const float*)d_in[3];
    float* C = (float*)d_out;

    const int N = in_sizes[3];                        // 12288
    const long Bsz = (long)in_sizes[1];               // (K/16)*(2N)
    const int K = (int)(Bsz / (2L * N)) * 16;         // 4096
    const int M = (int)((long)in_sizes[0] / K);       // 4096
    const int T = K / 16;

    __hip_bfloat16* Ab = (__hip_bfloat16*)d_ws;                               // M*K*2 B
    __hip_bfloat16* Wt = (__hip_bfloat16*)((char*)d_ws + (size_t)M * K * 2);  // N*K*2 B

    const int n8 = (M * K) / 8;
    cvt_a_kernel<<<(n8 + 255) / 256, 256, 0, stream>>>(A, Ab, n8);
    dequant_kernel<<<dim3(T / 16, N / 16), 256, 0, stream>>>(Bp, s, Wt, N, T);
    gemm_bt_kernel<<<dim3(N / 128, M / 128), 256, 0, stream>>>(Ab, Wt, bias, C, M, N, K);
}

// Round 3
// 730.996 us; speedup vs baseline: 1.1292x; 1.0412x over previous
//
#include <hip/hip_runtime.h>
#include <hip/hip_bf16.h>

typedef __bf16 bf16x8 __attribute__((ext_vector_type(8)));
typedef float floatx4 __attribute__((ext_vector_type(4)));

#define AS1 __attribute__((address_space(1)))
#define AS3 __attribute__((address_space(3)))

// ---------------------------------------------------------------- cvt A fp32 -> bf16
__global__ __launch_bounds__(256) void cvt_a_kernel(const float* __restrict__ A,
                                                    __hip_bfloat16* __restrict__ Ab,
                                                    int n8) {
    int i = blockIdx.x * 256 + threadIdx.x;
    if (i >= n8) return;
    size_t base = (size_t)i * 8;
    float4 a0 = *(const float4*)(A + base);
    float4 a1 = *(const float4*)(A + base + 4);
    union { __hip_bfloat16 h[8]; float4 f; } u;
    u.h[0] = __float2bfloat16(a0.x);
    u.h[1] = __float2bfloat16(a0.y);
    u.h[2] = __float2bfloat16(a0.z);
    u.h[3] = __float2bfloat16(a0.w);
    u.h[4] = __float2bfloat16(a1.x);
    u.h[5] = __float2bfloat16(a1.y);
    u.h[6] = __float2bfloat16(a1.z);
    u.h[7] = __float2bfloat16(a1.w);
    *(float4*)(Ab + base) = u.f;
}

// ---------------------------------------------------------------- dequant B -> Wt bf16 [N][K]
// R2 failure: t-fast read map -> lanes strided 2N*4 B apart = 64 lines/wave,
// ~16x over-fetch, latency-bound (~190 us). Fix: n-fast reads (coalesced 8 B
// per lane), LDS transpose, t-fast 32 B writes (coalesced).
// Block tile: 16 t-rows x 64 n-cols. LDS row stride 264 elems = 528 B:
// 16 B-aligned for float4, and 132 dwords = 33 bank-groups -> phase-1 write
// lanes (consecutive n) land on consecutive 4-bank groups (conflict-benign).
__global__ __launch_bounds__(256) void dequant_kernel(const int* __restrict__ Bp,
                                                      const float* __restrict__ s,
                                                      __hip_bfloat16* __restrict__ Wt,
                                                      int N, int T) {
    __shared__ __hip_bfloat16 tile[64][264];  // [n][t*16+r], padded stride
    const int tid = threadIdx.x;
    const int t0 = blockIdx.x * 16;
    const int n0 = blockIdx.y * 64;
    const int K = T * 16;

    {
        const int nl = tid & 63;   // n fast -> coalesced packed reads
        const int tg = tid >> 6;   // wave id = t-group
#pragma unroll
        for (int tt = 0; tt < 4; ++tt) {
            const int tl = tg * 4 + tt;
            const int t = t0 + tl;
            const int n = n0 + nl;
            const int2 p = *(const int2*)(Bp + (size_t)t * (2 * N) + 2 * n);
            const unsigned lo = (unsigned)p.x;
            const unsigned hi = (unsigned)p.y;
            const float sc = s[(size_t)(t >> 3) * N + n];  // group row = t/8
            union { __hip_bfloat16 h[16]; float4 f[2]; } u;
#pragma unroll
            for (int r = 0; r < 8; ++r) {
                u.h[r]     = __float2bfloat16(((float)((lo >> (4 * r)) & 0xFu) - 8.0f) * sc);
                u.h[r + 8] = __float2bfloat16(((float)((hi >> (4 * r)) & 0xFu) - 8.0f) * sc);
            }
            *(float4*)&tile[nl][tl * 16]     = u.f[0];
            *(float4*)&tile[nl][tl * 16 + 8] = u.f[1];
        }
    }
    __syncthreads();
    {
        const int tl = tid & 15;   // t fast -> coalesced Wt writes
        const int nq = tid >> 4;
#pragma unroll
        for (int p = 0; p < 4; ++p) {
            const int n = p * 16 + nq;
            float4 v0 = *(const float4*)&tile[n][tl * 16];
            float4 v1 = *(const float4*)&tile[n][tl * 16 + 8];
            float4* dst = (float4*)(Wt + (size_t)(n0 + n) * K + (size_t)(t0 + tl) * 16);
            dst[0] = v0;
            dst[1] = v1;
        }
    }
}

// ---------------------------------------------------------------- GEMM C = A * Wt^T + bias
// A  bf16 [M][K] row-major, Bt bf16 [N][K] row-major (i.e. W^T), C fp32 [M][N].
// 128x128 block tile, BK=64, 256 thr = 4 waves in 2x2, each wave 64x64 via
// 4x4 grid of 16x16x32 bf16 MFMA. global_load_lds width=16 staging (m97).
// Global-side XOR swizzle kills LDS read conflicts (R2: 1.5e8 -> 0).
// R3: rasterization swizzle (8 x-tiles x full y = 256-block groups) keeps the
// co-resident working set ~40 MB (fits LLC); nontemporal C stores stop the
// 192 MB C stream from evicting A/Wt.
__global__ __launch_bounds__(256) void gemm_bt_kernel(const __hip_bfloat16* __restrict__ A,
                                                      const __hip_bfloat16* __restrict__ Bt,
                                                      const float* __restrict__ bias,
                                                      float* __restrict__ C,
                                                      int M, int N, int K) {
    __shared__ __hip_bfloat16 As[128 * 64];
    __shared__ __hip_bfloat16 Bs[128 * 64];

    // ---- rasterization swizzle: y-fast within groups of 8 x-tiles
    int bx, by;
    {
        const int flat = blockIdx.y * gridDim.x + blockIdx.x;
        const int gy = gridDim.y;
        const int per = 8 * gy;
        const int g = flat / per;
        const int r = flat - g * per;
        const int xi = r / gy;
        bx = g * 8 + xi;
        by = r - xi * gy;
        if (bx >= (int)gridDim.x) { bx = blockIdx.x; by = blockIdx.y; }  // ragged-tail guard
    }

    const int tid = threadIdx.x;
    const int wave = tid >> 6;
    const int lane = tid & 63;
    const int m0 = by * 128;
    const int n0 = bx * 128;
    const int wm = wave >> 1;  // 0..1
    const int wn = wave & 1;   // 0..1

    floatx4 acc[4][4];
#pragma unroll
    for (int i = 0; i < 4; ++i)
#pragma unroll
        for (int j = 0; j < 4; ++j) acc[i][j] = (floatx4){0.f, 0.f, 0.f, 0.f};

    // staging: wave covers 8 rows per issue (8 lanes x 16B per row of 128B)
    const int ldrow = wave * 8 + (lane >> 3);              // 0..31
    const int swz = lane >> 3;                             // = ldrow & 7
    const int ldcol = (((lane & 7) ^ swz)) * 8;            // swizzled 16B chunk
    const __hip_bfloat16* Aldg = A + (size_t)(m0 + ldrow) * K + ldcol;
    const __hip_bfloat16* Bldg = Bt + (size_t)(n0 + ldrow) * K + ldcol;
    __hip_bfloat16* AsBase = &As[(wave * 8) * 64];  // wave-uniform LDS dst base
    __hip_bfloat16* BsBase = &Bs[(wave * 8) * 64];

    for (int k0 = 0; k0 < K; k0 += 64) {
#pragma unroll
        for (int i = 0; i < 4; ++i) {
            __builtin_amdgcn_global_load_lds((AS1 void*)(Aldg + (size_t)(i * 32) * K + k0),
                                             (AS3 void*)(AsBase + i * 32 * 64), 16, 0, 0);
            __builtin_amdgcn_global_load_lds((AS1 void*)(Bldg + (size_t)(i * 32) * K + k0),
                                             (AS3 void*)(BsBase + i * 32 * 64), 16, 0, 0);
        }
        __syncthreads();  // drains vmcnt(0) then barrier

#pragma unroll
        for (int ks = 0; ks < 2; ++ks) {
            // global chunk t = ks*4 + quad; LDS chunk = t ^ (m_row & 7),
            // m_row & 7 == lane & 7 (wm*64, i*16 are multiples of 8)
            const int koff = ((ks * 4 + (lane >> 4)) ^ (lane & 7)) * 8;
            bf16x8 af[4], bfr[4];
#pragma unroll
            for (int i = 0; i < 4; ++i)
                af[i] = *(const bf16x8*)&As[(wm * 64 + i * 16 + (lane & 15)) * 64 + koff];
#pragma unroll
            for (int j = 0; j < 4; ++j)
                bfr[j] = *(const bf16x8*)&Bs[(wn * 64 + j * 16 + (lane & 15)) * 64 + koff];
#pragma unroll
            for (int i = 0; i < 4; ++i)
#pragma unroll
                for (int j = 0; j < 4; ++j)
                    acc[i][j] = __builtin_amdgcn_mfma_f32_16x16x32_bf16(af[i], bfr[j],
                                                                        acc[i][j], 0, 0, 0);
        }
        __syncthreads();
    }

    // epilogue: C/D layout col=lane&15, row=(lane>>4)*4+reg  [m89-verified]
    const int cl = lane & 15;
    const int rq = (lane >> 4) * 4;
#pragma unroll
    for (int j = 0; j < 4; ++j) {
        const int n = n0 + wn * 64 + j * 16 + cl;
        const float bv = bias[n];
#pragma unroll
        for (int i = 0; i < 4; ++i) {
            const int mbase = m0 + wm * 64 + i * 16 + rq;
#pragma unroll
            for (int r = 0; r < 4; ++r) {
                float v = acc[i][j][r] + bv;
                __builtin_nontemporal_store(v, &C[(size_t)(mbase + r) * N + n]);
            }
        }
    }
}

// ---------------------------------------------------------------- launch
extern "C" void kernel_launch(void* const* d_in, const int* in_sizes, int n_in,
                              void* d_out, int out_size, void* d_ws, size_t ws_size,
                              hipStream_t stream) {
    const float* A = (const float*)d_in[0];
    const int* Bp = (const int*)d_in[1];
    const float* s = (const float*)d_in[2];
    const float* bias = (const float*)d_in[3];
    float* C = (float*)d_out;

    const int N = in_sizes[3];                        // 12288
    const long Bsz = (long)in_sizes[1];               // (K/16)*(2N)
    const int K = (int)(Bsz / (2L * N)) * 16;         // 4096
    const int M = (int)((long)in_sizes[0] / K);       // 4096
    const int T = K / 16;

    __hip_bfloat16* Ab = (__hip_bfloat16*)d_ws;                               // M*K*2 B
    __hip_bfloat16* Wt = (__hip_bfloat16*)((char*)d_ws + (size_t)M * K * 2);  // N*K*2 B

    const int n8 = (M * K) / 8;
    cvt_a_kernel<<<(n8 + 255) / 256, 256, 0, stream>>>(A, Ab, n8);
    dequant_kernel<<<dim3(T / 16, N / 64), 256, 0, stream>>>(Bp, s, Wt, N, T);
    gemm_bt_kernel<<<dim3(N / 128, M / 128), 256, 0, stream>>>(Ab, Wt, bias, C, M, N, K);
}